// Round 8
// baseline (122.043 us; speedup 1.0000x reference)
//
#include <hip/hip_runtime.h>
#include <stdint.h>

// BiasedFeatureDropout: out = x * mask * 1.25, mask from JAX threefry PRNG
// (partitionable path: bits[i] = o0^o1 of threefry2x32(key=(0,1), (0, i)))
// keep iff bits < T*512, T = 1677722 (bias ch<32) / 6710887 (regular)
// (integer form of u < 0.2f / 0.8f, verified bit-exact R1-R7)
//
// R8: I-fetch theory. R6/R7 fully unrolled = ~8.5KB straight-line code;
// VALU busy-time invariant at ~65-69% issue => suspect SQ fetch can't feed
// 4 SIMDs of unique VOP3 stream. Keep R6 memory structure (4 loads hoisted
// BEFORE any store -> in-order vmcnt never makes load-waits drain NT
// stores), but loop over the 4 streams (#pragma unroll 1): hot loop ~2.2KB.

typedef float v4f __attribute__((ext_vector_type(4)));

#define ROTL(x, n) __builtin_amdgcn_alignbit((x), (x), 32 - (n))

__device__ __forceinline__ uint32_t threefry_bits(uint32_t i) {
    const uint32_t KS2 = 0x1BD11BDBu;   // 0 ^ 1 ^ 0x1BD11BDA
    uint32_t x1 = i + 1u;               // lo + ks1
    uint32_t x0 = x1;                   // round-1 add vs x0=0
    x1 = ROTL(x1, 13) ^ x0;
    x0 += x1; x1 = ROTL(x1, 15) ^ x0;
    x0 += x1; x1 = ROTL(x1, 26) ^ x0;
    x0 += x1; x1 = ROTL(x1,  6) ^ x0;
    x1 += KS2 + 1u;                     // inj1
    x0 = x0 + x1 + 1u;
    x1 = ROTL(x1, 17) ^ x0;
    x0 += x1; x1 = ROTL(x1, 29) ^ x0;
    x0 += x1; x1 = ROTL(x1, 16) ^ x0;
    x0 += x1; x1 = ROTL(x1, 24) ^ x0;
    x1 += 2u;                           // inj2
    x0 = x0 + x1 + KS2;
    x1 = ROTL(x1, 13) ^ x0;
    x0 += x1; x1 = ROTL(x1, 15) ^ x0;
    x0 += x1; x1 = ROTL(x1, 26) ^ x0;
    x0 += x1; x1 = ROTL(x1,  6) ^ x0;
    x1 += 4u;                           // inj3 (x0 += 0)
    x0 += x1;
    x1 = ROTL(x1, 17) ^ x0;
    x0 += x1; x1 = ROTL(x1, 29) ^ x0;
    x0 += x1; x1 = ROTL(x1, 16) ^ x0;
    x0 += x1; x1 = ROTL(x1, 24) ^ x0;
    x1 += KS2 + 4u;                     // inj4
    x0 = x0 + x1 + 1u;
    x1 = ROTL(x1, 13) ^ x0;
    x0 += x1; x1 = ROTL(x1, 15) ^ x0;
    x0 += x1; x1 = ROTL(x1, 26) ^ x0;
    x0 += x1; x1 = ROTL(x1,  6) ^ x0;
    return (x0 + KS2) ^ (x1 + 5u);      // inj5 + output xor
}

__global__ __launch_bounds__(256) void BiasedFeatureDropout_kernel(
        const v4f* __restrict__ x, v4f* __restrict__ out) {
    const uint32_t Q4 = 3211264u;     // float4s per quarter = n/16
    const uint32_t QE = 12845056u;    // elems per quarter = 16*CHW
    uint32_t t = blockIdx.x * 256u + threadIdx.x;   // < Q4

    uint32_t base = t * 4u;
    // quarter offset QE == 0 (mod CHW) -> all 4 streams share channel class
    uint32_t T = ((base % 802816u) < 100352u) ? (1677722u << 9)
                                              : (6710887u << 9);

    // all 4 loads in flight before ANY store is issued: in-order vmcnt
    // retirement means later load-waits never drain NT stores
    v4f d[4];
    d[0] = x[t];
    d[1] = x[t + Q4];
    d[2] = x[t + 2u * Q4];
    d[3] = x[t + 3u * Q4];

    // compact hot loop (~2.2KB) instead of 8.5KB straight-line: relieve
    // SQ instruction fetch; loop overhead ~5 scalar ops/iter
    #pragma unroll 1
    for (uint32_t s = 0; s < 4u; ++s) {
        uint32_t c = base + s * QE;
        v4f dv = d[s];
        v4f o;
        #pragma unroll
        for (int k = 0; k < 4; ++k) {
            uint32_t bits = threefry_bits(c + (uint32_t)k);
            o[k] = (bits < T) ? dv[k] * 1.25f : 0.0f;
        }
        __builtin_nontemporal_store(o, &out[t + s * Q4]);
    }
}

extern "C" void kernel_launch(void* const* d_in, const int* in_sizes, int n_in,
                              void* d_out, int out_size, void* d_ws, size_t ws_size,
                              hipStream_t stream) {
    const float* x = (const float*)d_in[0];
    float* out = (float*)d_out;
    // n = 51,380,224 = 16 * 3,211,264; blocks = 3,211,264/256 = 12,544 exact
    int block = 256;
    int grid = 12544;
    BiasedFeatureDropout_kernel<<<grid, block, 0, stream>>>(
        (const v4f*)x, (v4f*)out);
}

// Round 9
// 93.874 us; speedup vs baseline: 1.3001x; 1.3001x over previous
//
#include <hip/hip_runtime.h>
#include <stdint.h>

// BiasedFeatureDropout: out = x * mask * 1.25, mask from JAX threefry PRNG
// (partitionable path: bits[i] = o0^o1 of threefry2x32(key=(0,1), (0, i)))
// keep iff bits < T*512, T = 1677722 (bias ch<32) / 6710887 (regular)
// (integer form of u < 0.2f / 0.8f, verified bit-exact R1-R8)
//
// R9 = R7 revert (best: 94.39us). R8's compact loop REGRESSED (122us):
// runtime-indexed d[s] in a #pragma unroll 1 loop (rule #20) + store-in-loop
// vmcnt pattern added ~35% VALU busy-time. Fully-unrolled one-shot wins.
// Plateau evidence: R3=R5=R6=R7 at 94.4-94.6us; VALU busy-cycles invariant;
// issue fraction ~66% == m07 uBench's sustained fraction of nominal VALU.

typedef float v4f __attribute__((ext_vector_type(4)));

#define ROTL(x, n) __builtin_amdgcn_alignbit((x), (x), 32 - (n))

__device__ __forceinline__ uint32_t threefry_bits(uint32_t i) {
    const uint32_t KS2 = 0x1BD11BDBu;   // 0 ^ 1 ^ 0x1BD11BDA
    uint32_t x1 = i + 1u;               // lo + ks1
    uint32_t x0 = x1;                   // round-1 add vs x0=0
    x1 = ROTL(x1, 13) ^ x0;
    x0 += x1; x1 = ROTL(x1, 15) ^ x0;
    x0 += x1; x1 = ROTL(x1, 26) ^ x0;
    x0 += x1; x1 = ROTL(x1,  6) ^ x0;
    x1 += KS2 + 1u;                     // inj1
    x0 = x0 + x1 + 1u;
    x1 = ROTL(x1, 17) ^ x0;
    x0 += x1; x1 = ROTL(x1, 29) ^ x0;
    x0 += x1; x1 = ROTL(x1, 16) ^ x0;
    x0 += x1; x1 = ROTL(x1, 24) ^ x0;
    x1 += 2u;                           // inj2
    x0 = x0 + x1 + KS2;
    x1 = ROTL(x1, 13) ^ x0;
    x0 += x1; x1 = ROTL(x1, 15) ^ x0;
    x0 += x1; x1 = ROTL(x1, 26) ^ x0;
    x0 += x1; x1 = ROTL(x1,  6) ^ x0;
    x1 += 4u;                           // inj3 (x0 += 0)
    x0 += x1;
    x1 = ROTL(x1, 17) ^ x0;
    x0 += x1; x1 = ROTL(x1, 29) ^ x0;
    x0 += x1; x1 = ROTL(x1, 16) ^ x0;
    x0 += x1; x1 = ROTL(x1, 24) ^ x0;
    x1 += KS2 + 4u;                     // inj4
    x0 = x0 + x1 + 1u;
    x1 = ROTL(x1, 13) ^ x0;
    x0 += x1; x1 = ROTL(x1, 15) ^ x0;
    x0 += x1; x1 = ROTL(x1, 26) ^ x0;
    x0 += x1; x1 = ROTL(x1,  6) ^ x0;
    return (x0 + KS2) ^ (x1 + 5u);      // inj5 + output xor
}

__global__ __launch_bounds__(256) void BiasedFeatureDropout_kernel(
        const v4f* __restrict__ x, v4f* __restrict__ out) {
    const uint32_t Q4 = 3211264u;     // float4s per quarter = n/16
    const uint32_t QE = 12845056u;    // elems per quarter = 16*CHW
    uint32_t t = blockIdx.x * 256u + threadIdx.x;   // < Q4

    uint32_t base = t * 4u;
    // quarter offset QE == 0 (mod CHW) -> all 4 streams share channel class
    uint32_t T = ((base % 802816u) < 100352u) ? (1677722u << 9)
                                              : (6710887u << 9);

    v4f d0 = x[t];
    v4f d1 = x[t + Q4];
    v4f d2 = x[t + 2u * Q4];
    v4f d3 = x[t + 3u * Q4];

    uint32_t bits[16];
    #pragma unroll
    for (int s = 0; s < 4; ++s) {
        uint32_t c = base + (uint32_t)s * QE;
        #pragma unroll
        for (int k = 0; k < 4; ++k)
            bits[s * 4 + k] = threefry_bits(c + (uint32_t)k);
    }

    v4f o0, o1, o2, o3;
    #pragma unroll
    for (int k = 0; k < 4; ++k) {
        o0[k] = (bits[k]      < T) ? d0[k] * 1.25f : 0.0f;
        o1[k] = (bits[4 + k]  < T) ? d1[k] * 1.25f : 0.0f;
        o2[k] = (bits[8 + k]  < T) ? d2[k] * 1.25f : 0.0f;
        o3[k] = (bits[12 + k] < T) ? d3[k] * 1.25f : 0.0f;
    }
    __builtin_nontemporal_store(o0, &out[t]);
    __builtin_nontemporal_store(o1, &out[t + Q4]);
    __builtin_nontemporal_store(o2, &out[t + 2u * Q4]);
    __builtin_nontemporal_store(o3, &out[t + 3u * Q4]);
}

extern "C" void kernel_launch(void* const* d_in, const int* in_sizes, int n_in,
                              void* d_out, int out_size, void* d_ws, size_t ws_size,
                              hipStream_t stream) {
    const float* x = (const float*)d_in[0];
    float* out = (float*)d_out;
    // n = 51,380,224 = 16 * 3,211,264; blocks = 3,211,264/256 = 12,544 exact
    int block = 256;
    int grid = 12544;
    BiasedFeatureDropout_kernel<<<grid, block, 0, stream>>>(
        (const v4f*)x, (v4f*)out);
}